// Round 7
// baseline (284.915 us; speedup 1.0000x reference)
//
#include <hip/hip_runtime.h>

#define ALPHA 0.2f
#define LDA 136   // LDS row stride in shorts (272 B: aligned, conflict-balanced)

typedef short bf16x8 __attribute__((ext_vector_type(8)));
typedef float f32x4  __attribute__((ext_vector_type(4)));

static __device__ __forceinline__ float bf2f(unsigned short u) {
    union { unsigned int i; float f; } v; v.i = ((unsigned int)u) << 16; return v.f;
}
static __device__ __forceinline__ unsigned short f2bf(float f) {
    union { float f; unsigned int i; } v; v.f = f;
    unsigned int x = v.i;
    return (unsigned short)((x + 0x7fffu + ((x >> 16) & 1u)) >> 16);  // RNE
}

// One-time: wT[c][k] = bf16(w[k][c]) for w1 (block 0) and w2 (block 1).
__global__ __launch_bounds__(256)
void prep_wT_kernel(const float* __restrict__ w1, const float* __restrict__ w2,
                    unsigned short* __restrict__ wT1, unsigned short* __restrict__ wT2)
{
    __shared__ unsigned short wL[128 * 130];   // +2 pad: conflict-free transpose
    const float* w = blockIdx.x ? w2 : w1;
    unsigned short* wT = blockIdx.x ? wT2 : wT1;
    const int tid = threadIdx.x;

    for (int i = 0; i < 16; i++) {             // 4096 float4 units
        int e = tid + i * 256;
        int k = e >> 5, c0 = (e & 31) * 4;
        float4 v = *(const float4*)&w[k * 128 + c0];
        wL[(c0 + 0) * 130 + k] = f2bf(v.x);
        wL[(c0 + 1) * 130 + k] = f2bf(v.y);
        wL[(c0 + 2) * 130 + k] = f2bf(v.z);
        wL[(c0 + 3) * 130 + k] = f2bf(v.w);
    }
    __syncthreads();
    for (int i = 0; i < 8; i++) {              // 2048 ushort8 units
        int e = tid + i * 256;
        int c = e >> 4, k0 = (e & 15) * 8;
        ushort4 a, b;
        a.x = wL[c * 130 + k0 + 0]; a.y = wL[c * 130 + k0 + 1];
        a.z = wL[c * 130 + k0 + 2]; a.w = wL[c * 130 + k0 + 3];
        b.x = wL[c * 130 + k0 + 4]; b.y = wL[c * 130 + k0 + 5];
        b.z = wL[c * 130 + k0 + 6]; b.w = wL[c * 130 + k0 + 7];
        *(ushort4*)&wT[c * 128 + k0]     = a;
        *(ushort4*)&wT[c * 128 + k0 + 4] = b;
    }
}

// MFMA GEMM + fused score dots (unchanged from round 5).
template <bool SRC_BF>
__global__ __launch_bounds__(256)
void gemm_score_mfma(const void* __restrict__ srcv,
                     const unsigned short* __restrict__ wT,   // [c][k] bf16
                     const float* __restrict__ a_in,
                     const float* __restrict__ a_out,
                     unsigned short* __restrict__ hid,
                     float* __restrict__ s_in,
                     float* __restrict__ s_out,
                     int n)
{
    __shared__ short As[64 * LDA];
    __shared__ short Bs[128 * LDA];
    __shared__ float aS[2][128];

    const int tid = threadIdx.x;
    const int rbase = blockIdx.x * 64;

    if (tid < 128) { aS[0][tid] = a_in[tid]; aS[1][tid] = a_out[tid]; }

    if (SRC_BF) {
        const unsigned short* src = (const unsigned short*)srcv;
        #pragma unroll
        for (int i = 0; i < 8; i++) {
            int e = tid + i * 256;
            int r = e >> 5, c4 = (e & 31) * 4;
            int gr = rbase + r;
            ushort4 v;
            if (gr < n) v = *(const ushort4*)&src[(size_t)gr * 128 + c4];
            else { v.x = v.y = v.z = v.w = 0; }
            *(ushort4*)&As[r * LDA + c4] = v;
        }
    } else {
        const float* src = (const float*)srcv;
        #pragma unroll
        for (int i = 0; i < 8; i++) {
            int e = tid + i * 256;
            int r = e >> 5, c4 = (e & 31) * 4;
            int gr = rbase + r;
            ushort4 u;
            if (gr < n) {
                float4 v = *(const float4*)&src[(size_t)gr * 128 + c4];
                u.x = f2bf(v.x); u.y = f2bf(v.y); u.z = f2bf(v.z); u.w = f2bf(v.w);
            } else { u.x = u.y = u.z = u.w = 0; }
            *(ushort4*)&As[r * LDA + c4] = u;
        }
    }
    #pragma unroll
    for (int i = 0; i < 8; i++) {
        int e = tid + i * 256;
        int nr = e >> 4, j = (e & 15) * 8;
        int4 v = *(const int4*)&wT[nr * 128 + j];
        *(int4*)&Bs[nr * LDA + j] = v;
    }
    __syncthreads();

    const int lane = tid & 63;
    const int wv = tid >> 6;
    const int m = lane & 15;
    const int q = lane >> 4;

    f32x4 acc[8];
    #pragma unroll
    for (int t = 0; t < 8; t++) acc[t] = (f32x4){0.f, 0.f, 0.f, 0.f};

    const short* Abase = &As[(wv * 16 + m) * LDA + q * 8];
    const short* Bbase = &Bs[m * LDA + q * 8];

    #pragma unroll
    for (int ks = 0; ks < 4; ks++) {
        bf16x8 aF = *(const bf16x8*)(Abase + ks * 32);
        #pragma unroll
        for (int t = 0; t < 8; t++) {
            bf16x8 bF = *(const bf16x8*)(Bbase + t * 16 * LDA + ks * 32);
            acc[t] = __builtin_amdgcn_mfma_f32_16x16x32_bf16(aF, bF, acc[t], 0, 0, 0);
        }
    }

    float pin[4] = {0.f, 0.f, 0.f, 0.f}, pout[4] = {0.f, 0.f, 0.f, 0.f};
    #pragma unroll
    for (int t = 0; t < 8; t++) {
        float ai = aS[0][t * 16 + m];
        float ao = aS[1][t * 16 + m];
        #pragma unroll
        for (int r = 0; r < 4; r++) {
            pin[r]  += acc[t][r] * ai;
            pout[r] += acc[t][r] * ao;
        }
    }
    #pragma unroll
    for (int msk = 8; msk >= 1; msk >>= 1) {
        #pragma unroll
        for (int r = 0; r < 4; r++) {
            pin[r]  += __shfl_xor(pin[r],  msk);
            pout[r] += __shfl_xor(pout[r], msk);
        }
    }
    if (m == 0) {
        #pragma unroll
        for (int r = 0; r < 4; r++) {
            int g = rbase + wv * 16 + q * 4 + r;
            if (g < n) { s_in[g] = pin[r]; s_out[g] = pout[r]; }
        }
    }

    #pragma unroll
    for (int t = 0; t < 8; t++)
        #pragma unroll
        for (int r = 0; r < 4; r++)
            As[(wv * 16 + q * 4 + r) * LDA + t * 16 + m] = (short)f2bf(acc[t][r]);
    __syncthreads();
    #pragma unroll
    for (int i = 0; i < 4; i++) {
        int e = tid + i * 256;
        int r = e >> 4, j = (e & 15) * 8;
        int gr = rbase + r;
        if (gr < n) {
            int4 v = *(const int4*)&As[r * LDA + j];
            *(int4*)&hid[(size_t)gr * 128 + j] = v;
        }
    }
}

// Per-edge normalized attention weights: 1 thread/edge, 16 lanes per node.
// we[n*16+k] = adj * softmax_k(leakyrelu(s_in[n] + s_out[dst]))
__global__ __launch_bounds__(256)
void edge_weights_kernel(const float* __restrict__ s_in,
                         const float* __restrict__ s_out,
                         const int* __restrict__ dst,
                         const float* __restrict__ adj,
                         float* __restrict__ we,
                         int n)
{
    const int idx = blockIdx.x * 256 + threadIdx.x;   // edge index
    const int node = idx >> 4;
    if (node >= n) return;

    const int dk = dst[idx];
    float t = s_in[node] + s_out[dk];                 // s_out: 400 KB, L2-hot
    float e = (t > 0.f) ? t : ALPHA * t;              // LeakyReLU(0.2)

    float m = e;                                       // max over the 16-lane group
    #pragma unroll
    for (int msk = 8; msk >= 1; msk >>= 1) m = fmaxf(m, __shfl_xor(m, msk));
    float p = __expf(e - m);
    float s = p;
    #pragma unroll
    for (int msk = 8; msk >= 1; msk >>= 1) s += __shfl_xor(s, msk);

    we[idx] = adj[idx] * p / s;
}

// Pure gather: one wave per node, lane owns 2 cols.
// out = relu( sum_k we[k]*hid[dk[k]] + b ).  No softmax, no shuffles.
template <bool FINAL>
__global__ __launch_bounds__(256)
void gat_gather_kernel(const unsigned short* __restrict__ hid,
                       const int* __restrict__ dst,
                       const float* __restrict__ we,
                       const float* __restrict__ bias,
                       void* __restrict__ outv,
                       int n)
{
    const int lane = threadIdx.x & 63;
    const int node = (blockIdx.x * 256 + threadIdx.x) >> 6;
    if (node >= n) return;

    int dk[16];
    float wk[16];
    #pragma unroll
    for (int j = 0; j < 4; j++) {          // wave-uniform 16B loads
        int4   dv = *(const int4*)&dst[node * 16 + j * 4];
        float4 wv = *(const float4*)&we[node * 16 + j * 4];
        dk[j * 4 + 0] = dv.x; dk[j * 4 + 1] = dv.y;
        dk[j * 4 + 2] = dv.z; dk[j * 4 + 3] = dv.w;
        wk[j * 4 + 0] = wv.x; wk[j * 4 + 1] = wv.y;
        wk[j * 4 + 2] = wv.z; wk[j * 4 + 3] = wv.w;
    }

    const int c = lane * 2;
    float accx = 0.f, accy = 0.f;
    #pragma unroll
    for (int k = 0; k < 16; k++) {         // 16 independent 256 B row reads
        ushort2 hq = *(const ushort2*)&hid[(size_t)dk[k] * 128 + c];
        accx += wk[k] * bf2f(hq.x);
        accy += wk[k] * bf2f(hq.y);
    }
    float ox = fmaxf(accx + bias[c],     0.f);
    float oy = fmaxf(accy + bias[c + 1], 0.f);

    const size_t oidx = (size_t)node * 128 + c;
    if (FINAL) {
        *(float2*)&((float*)outv)[oidx] = make_float2(ox, oy);
    } else {
        ushort2 ov; ov.x = f2bf(ox); ov.y = f2bf(oy);
        *(ushort2*)&((unsigned short*)outv)[oidx] = ov;
    }
}

extern "C" void kernel_launch(void* const* d_in, const int* in_sizes, int n_in,
                              void* d_out, int out_size, void* d_ws, size_t ws_size,
                              hipStream_t stream)
{
    const float* x      = (const float*)d_in[0];
    const int*   dst    = (const int*)d_in[1];
    const float* adj    = (const float*)d_in[2];
    const float* w1     = (const float*)d_in[3];
    const float* a_in1  = (const float*)d_in[4];
    const float* a_out1 = (const float*)d_in[5];
    const float* b1     = (const float*)d_in[6];
    const float* w2     = (const float*)d_in[7];
    const float* a_in2  = (const float*)d_in[8];
    const float* a_out2 = (const float*)d_in[9];
    const float* b2     = (const float*)d_in[10];

    const int N = in_sizes[0] / 128;               // 100000

    // ws: hid bf16 (25.6MB) | s_in | s_out | we (6.4MB) | wT1 | wT2  ~33 MB
    unsigned short* hid   = (unsigned short*)d_ws;
    float*          s_in  = (float*)(hid + (size_t)N * 128);
    float*          s_out = s_in + N;
    float*          we    = s_out + N;
    unsigned short* wT1   = (unsigned short*)(we + (size_t)N * 16);
    unsigned short* wT2   = wT1 + 128 * 128;
    // layer-1 activation h1 (bf16) lives in the upper half of the fp32 d_out
    unsigned short* h1    = (unsigned short*)d_out + out_size;

    dim3 blk(256);
    dim3 ggrid((N + 63) / 64);                     // 1563
    dim3 egrid((N * 16 + 255) / 256);              // 6250 (1 thread/edge)
    dim3 agrid((N + 3) / 4);                       // 25000 (1 node/wave)

    prep_wT_kernel<<<2, blk, 0, stream>>>(w1, w2, wT1, wT2);

    // Layer 1
    gemm_score_mfma<false><<<ggrid, blk, 0, stream>>>(x,  wT1, a_in1, a_out1,
                                                      hid, s_in, s_out, N);
    edge_weights_kernel<<<egrid, blk, 0, stream>>>(s_in, s_out, dst, adj, we, N);
    gat_gather_kernel<false><<<agrid, blk, 0, stream>>>(hid, dst, we, b1, h1, N);
    // Layer 2
    gemm_score_mfma<true><<<ggrid, blk, 0, stream>>>(h1, wT2, a_in2, a_out2,
                                                     hid, s_in, s_out, N);
    edge_weights_kernel<<<egrid, blk, 0, stream>>>(s_in, s_out, dst, adj, we, N);
    gat_gather_kernel<true><<<agrid, blk, 0, stream>>>(hid, dst, we, b2, d_out, N);
}

// Round 8
// 275.966 us; speedup vs baseline: 1.0324x; 1.0324x over previous
//
#include <hip/hip_runtime.h>

#define ALPHA 0.2f
#define LDA 136   // LDS row stride in shorts (272 B: aligned, conflict-balanced)

typedef short bf16x8 __attribute__((ext_vector_type(8)));
typedef float f32x4  __attribute__((ext_vector_type(4)));

static __device__ __forceinline__ float bf2f(unsigned short u) {
    union { unsigned int i; float f; } v; v.i = ((unsigned int)u) << 16; return v.f;
}
static __device__ __forceinline__ unsigned short f2bf(float f) {
    union { float f; unsigned int i; } v; v.f = f;
    unsigned int x = v.i;
    return (unsigned short)((x + 0x7fffu + ((x >> 16) & 1u)) >> 16);  // RNE
}

// One-time: wT[c][k] = bf16(w[k][c]) for w1 (block 0) and w2 (block 1).
__global__ __launch_bounds__(256)
void prep_wT_kernel(const float* __restrict__ w1, const float* __restrict__ w2,
                    unsigned short* __restrict__ wT1, unsigned short* __restrict__ wT2)
{
    __shared__ unsigned short wL[128 * 130];
    const float* w = blockIdx.x ? w2 : w1;
    unsigned short* wT = blockIdx.x ? wT2 : wT1;
    const int tid = threadIdx.x;

    for (int i = 0; i < 16; i++) {
        int e = tid + i * 256;
        int k = e >> 5, c0 = (e & 31) * 4;
        float4 v = *(const float4*)&w[k * 128 + c0];
        wL[(c0 + 0) * 130 + k] = f2bf(v.x);
        wL[(c0 + 1) * 130 + k] = f2bf(v.y);
        wL[(c0 + 2) * 130 + k] = f2bf(v.z);
        wL[(c0 + 3) * 130 + k] = f2bf(v.w);
    }
    __syncthreads();
    for (int i = 0; i < 8; i++) {
        int e = tid + i * 256;
        int c = e >> 4, k0 = (e & 15) * 8;
        ushort4 a, b;
        a.x = wL[c * 130 + k0 + 0]; a.y = wL[c * 130 + k0 + 1];
        a.z = wL[c * 130 + k0 + 2]; a.w = wL[c * 130 + k0 + 3];
        b.x = wL[c * 130 + k0 + 4]; b.y = wL[c * 130 + k0 + 5];
        b.z = wL[c * 130 + k0 + 6]; b.w = wL[c * 130 + k0 + 7];
        *(ushort4*)&wT[c * 128 + k0]     = a;
        *(ushort4*)&wT[c * 128 + k0 + 4] = b;
    }
}

// MFMA GEMM + fused score dots (unchanged).
template <bool SRC_BF>
__global__ __launch_bounds__(256)
void gemm_score_mfma(const void* __restrict__ srcv,
                     const unsigned short* __restrict__ wT,   // [c][k] bf16
                     const float* __restrict__ a_in,
                     const float* __restrict__ a_out,
                     unsigned short* __restrict__ hid,
                     float* __restrict__ s_in,
                     float* __restrict__ s_out,
                     int n)
{
    __shared__ short As[64 * LDA];
    __shared__ short Bs[128 * LDA];
    __shared__ float aS[2][128];

    const int tid = threadIdx.x;
    const int rbase = blockIdx.x * 64;

    if (tid < 128) { aS[0][tid] = a_in[tid]; aS[1][tid] = a_out[tid]; }

    if (SRC_BF) {
        const unsigned short* src = (const unsigned short*)srcv;
        #pragma unroll
        for (int i = 0; i < 8; i++) {
            int e = tid + i * 256;
            int r = e >> 5, c4 = (e & 31) * 4;
            int gr = rbase + r;
            ushort4 v;
            if (gr < n) v = *(const ushort4*)&src[(size_t)gr * 128 + c4];
            else { v.x = v.y = v.z = v.w = 0; }
            *(ushort4*)&As[r * LDA + c4] = v;
        }
    } else {
        const float* src = (const float*)srcv;
        #pragma unroll
        for (int i = 0; i < 8; i++) {
            int e = tid + i * 256;
            int r = e >> 5, c4 = (e & 31) * 4;
            int gr = rbase + r;
            ushort4 u;
            if (gr < n) {
                float4 v = *(const float4*)&src[(size_t)gr * 128 + c4];
                u.x = f2bf(v.x); u.y = f2bf(v.y); u.z = f2bf(v.z); u.w = f2bf(v.w);
            } else { u.x = u.y = u.z = u.w = 0; }
            *(ushort4*)&As[r * LDA + c4] = u;
        }
    }
    #pragma unroll
    for (int i = 0; i < 8; i++) {
        int e = tid + i * 256;
        int nr = e >> 4, j = (e & 15) * 8;
        int4 v = *(const int4*)&wT[nr * 128 + j];
        *(int4*)&Bs[nr * LDA + j] = v;
    }
    __syncthreads();

    const int lane = tid & 63;
    const int wv = tid >> 6;
    const int m = lane & 15;
    const int q = lane >> 4;

    f32x4 acc[8];
    #pragma unroll
    for (int t = 0; t < 8; t++) acc[t] = (f32x4){0.f, 0.f, 0.f, 0.f};

    const short* Abase = &As[(wv * 16 + m) * LDA + q * 8];
    const short* Bbase = &Bs[m * LDA + q * 8];

    #pragma unroll
    for (int ks = 0; ks < 4; ks++) {
        bf16x8 aF = *(const bf16x8*)(Abase + ks * 32);
        #pragma unroll
        for (int t = 0; t < 8; t++) {
            bf16x8 bF = *(const bf16x8*)(Bbase + t * 16 * LDA + ks * 32);
            acc[t] = __builtin_amdgcn_mfma_f32_16x16x32_bf16(aF, bF, acc[t], 0, 0, 0);
        }
    }

    float pin[4] = {0.f, 0.f, 0.f, 0.f}, pout[4] = {0.f, 0.f, 0.f, 0.f};
    #pragma unroll
    for (int t = 0; t < 8; t++) {
        float ai = aS[0][t * 16 + m];
        float ao = aS[1][t * 16 + m];
        #pragma unroll
        for (int r = 0; r < 4; r++) {
            pin[r]  += acc[t][r] * ai;
            pout[r] += acc[t][r] * ao;
        }
    }
    #pragma unroll
    for (int msk = 8; msk >= 1; msk >>= 1) {
        #pragma unroll
        for (int r = 0; r < 4; r++) {
            pin[r]  += __shfl_xor(pin[r],  msk);
            pout[r] += __shfl_xor(pout[r], msk);
        }
    }
    if (m == 0) {
        #pragma unroll
        for (int r = 0; r < 4; r++) {
            int g = rbase + wv * 16 + q * 4 + r;
            if (g < n) { s_in[g] = pin[r]; s_out[g] = pout[r]; }
        }
    }

    #pragma unroll
    for (int t = 0; t < 8; t++)
        #pragma unroll
        for (int r = 0; r < 4; r++)
            As[(wv * 16 + q * 4 + r) * LDA + t * 16 + m] = (short)f2bf(acc[t][r]);
    __syncthreads();
    #pragma unroll
    for (int i = 0; i < 4; i++) {
        int e = tid + i * 256;
        int r = e >> 4, j = (e & 15) * 8;
        int gr = rbase + r;
        if (gr < n) {
            int4 v = *(const int4*)&As[r * LDA + j];
            *(int4*)&hid[(size_t)gr * 128 + j] = v;
        }
    }
}

// Fused aggregate: one wave per node.
// Phase 1 (lanes 0-15): softmax over the node's 16 edges via 16-lane shuffles.
// Phase 2 (all 64 lanes): vectorized gather — 4 wave-loads of 1 KB; lane l
// reads 16 B (8 bf16 cols, octet (l&15)) of neighbor 4j+(l>>4); 8 shuffles
// broadcast (dk,wk); final cross-neighbor reduce = 16 shfl_xor adds.
template <bool FINAL>
__global__ __launch_bounds__(256)
void gat_aggregate_kernel(const unsigned short* __restrict__ hid,
                          const float* __restrict__ s_in,
                          const float* __restrict__ s_out,
                          const int* __restrict__ dst,
                          const float* __restrict__ adj,
                          const float* __restrict__ bias,
                          void* __restrict__ outv,
                          int n)
{
    const int lane = threadIdx.x & 63;
    const int node = (blockIdx.x * 256 + threadIdx.x) >> 6;
    if (node >= n) return;

    // --- softmax on lanes 0-15 ---
    float sc = -1e30f;
    int dk = 0;
    float av = 0.f;
    if (lane < 16) {
        int ei = node * 16 + lane;
        dk = dst[ei];
        av = adj[ei];
        float e = s_in[node] + s_out[dk];
        sc = (e > 0.f) ? e : ALPHA * e;            // LeakyReLU(0.2)
    }
    float m = sc;
    #pragma unroll
    for (int msk = 8; msk >= 1; msk >>= 1) m = fmaxf(m, __shfl_xor(m, msk));
    float p = (lane < 16) ? __expf(sc - m) : 0.f;
    float s = p;
    #pragma unroll
    for (int msk = 8; msk >= 1; msk >>= 1) s += __shfl_xor(s, msk);
    float wk = (lane < 16) ? av * p / s : 0.f;     // adj * softmax

    // --- broadcast neighbor (id, weight) for this lane's 4 gather slots ---
    const int sub = lane >> 4;        // which neighbor within each group of 4
    const int oct = lane & 15;        // column octet: cols oct*8 .. oct*8+7
    int   gdk[4];
    float gwk[4];
    #pragma unroll
    for (int j = 0; j < 4; j++) {
        gdk[j] = __shfl(dk, 4 * j + sub);
        gwk[j] = __shfl(wk, 4 * j + sub);
    }

    // --- gather: 4 x 1KB wave-loads, fp32 accumulate ---
    float acc[8];
    #pragma unroll
    for (int i = 0; i < 8; i++) acc[i] = 0.f;
    #pragma unroll
    for (int j = 0; j < 4; j++) {
        bf16x8 hv = *(const bf16x8*)&hid[(size_t)gdk[j] * 128 + oct * 8];
        float wj = gwk[j];
        #pragma unroll
        for (int i = 0; i < 8; i++)
            acc[i] += wj * bf2f((unsigned short)hv[i]);
    }
    // reduce across the 4 sub-groups (lanes with same oct, different sub)
    #pragma unroll
    for (int i = 0; i < 8; i++) {
        acc[i] += __shfl_xor(acc[i], 16);
        acc[i] += __shfl_xor(acc[i], 32);
    }

    // --- bias + relu + store (lanes 0-15 own the 16 octets) ---
    if (lane < 16) {
        float4 b0 = *(const float4*)&bias[oct * 8];
        float4 b1 = *(const float4*)&bias[oct * 8 + 4];
        float o[8];
        o[0] = fmaxf(acc[0] + b0.x, 0.f); o[1] = fmaxf(acc[1] + b0.y, 0.f);
        o[2] = fmaxf(acc[2] + b0.z, 0.f); o[3] = fmaxf(acc[3] + b0.w, 0.f);
        o[4] = fmaxf(acc[4] + b1.x, 0.f); o[5] = fmaxf(acc[5] + b1.y, 0.f);
        o[6] = fmaxf(acc[6] + b1.z, 0.f); o[7] = fmaxf(acc[7] + b1.w, 0.f);

        const size_t obase = (size_t)node * 128 + oct * 8;
        if (FINAL) {
            float* of = (float*)outv;
            *(float4*)&of[obase]     = make_float4(o[0], o[1], o[2], o[3]);
            *(float4*)&of[obase + 4] = make_float4(o[4], o[5], o[6], o[7]);
        } else {
            unsigned short* oh = (unsigned short*)outv;
            ushort4 u0, u1;
            u0.x = f2bf(o[0]); u0.y = f2bf(o[1]); u0.z = f2bf(o[2]); u0.w = f2bf(o[3]);
            u1.x = f2bf(o[4]); u1.y = f2bf(o[5]); u1.z = f2bf(o[6]); u1.w = f2bf(o[7]);
            *(ushort4*)&oh[obase]     = u0;
            *(ushort4*)&oh[obase + 4] = u1;
        }
    }
}

extern "C" void kernel_launch(void* const* d_in, const int* in_sizes, int n_in,
                              void* d_out, int out_size, void* d_ws, size_t ws_size,
                              hipStream_t stream)
{
    const float* x      = (const float*)d_in[0];
    const int*   dst    = (const int*)d_in[1];
    const float* adj    = (const float*)d_in[2];
    const float* w1     = (const float*)d_in[3];
    const float* a_in1  = (const float*)d_in[4];
    const float* a_out1 = (const float*)d_in[5];
    const float* b1     = (const float*)d_in[6];
    const float* w2     = (const float*)d_in[7];
    const float* a_in2  = (const float*)d_in[8];
    const float* a_out2 = (const float*)d_in[9];
    const float* b2     = (const float*)d_in[10];

    const int N = in_sizes[0] / 128;               // 100000

    // ws: hid bf16 (25.6MB) | s_in | s_out | wT1 | wT2
    unsigned short* hid   = (unsigned short*)d_ws;
    float*          s_in  = (float*)(hid + (size_t)N * 128);
    float*          s_out = s_in + N;
    unsigned short* wT1   = (unsigned short*)(s_out + N);
    unsigned short* wT2   = wT1 + 128 * 128;
    // layer-1 activation h1 (bf16) lives in the upper half of the fp32 d_out
    unsigned short* h1    = (unsigned short*)d_out + out_size;

    dim3 blk(256);
    dim3 ggrid((N + 63) / 64);                     // 1563
    dim3 agrid((N + 3) / 4);                       // 25000 (1 node/wave)

    prep_wT_kernel<<<2, blk, 0, stream>>>(w1, w2, wT1, wT2);

    // Layer 1
    gemm_score_mfma<false><<<ggrid, blk, 0, stream>>>(x,  wT1, a_in1, a_out1,
                                                      hid, s_in, s_out, N);
    gat_aggregate_kernel<false><<<agrid, blk, 0, stream>>>(hid, s_in, s_out, dst,
                                                           adj, b1, h1, N);
    // Layer 2
    gemm_score_mfma<true><<<ggrid, blk, 0, stream>>>(h1, wT2, a_in2, a_out2,
                                                     hid, s_in, s_out, N);
    gat_aggregate_kernel<true><<<agrid, blk, 0, stream>>>(hid, s_in, s_out, dst,
                                                          adj, b2, d_out, N);
}